// Round 11
// baseline (1529.398 us; speedup 1.0000x reference)
//
#include <hip/hip_runtime.h>

#define HW 65536
#define CH 64
#define NPIXF 4194304.0f

typedef __attribute__((ext_vector_type(8))) short short8;
typedef __attribute__((ext_vector_type(4))) short short4v;
typedef __attribute__((ext_vector_type(8))) __bf16 bf16x8;
typedef __attribute__((ext_vector_type(4))) float f32x4;

__device__ __forceinline__ unsigned short f2bf(float f) {
  unsigned int u = __builtin_bit_cast(unsigned int, f);
  u += 0x7FFFu + ((u >> 16) & 1u);
  return (unsigned short)(u >> 16);
}
__device__ __forceinline__ short cvt1(float f) {
  return __builtin_bit_cast(short, (__bf16)f);
}
__device__ __forceinline__ float fastrcp(float f) {
  return __builtin_amdgcn_rcpf(f);
}
__device__ __forceinline__ int swz(int p, int cc) { return cc ^ ((p ^ (p >> 3)) & 7); }

// ws layout:
//   floats wsf[16s+0..3]: sum_x, sumsq_x, sum_h, sumsq_h   (64B line/sample; bytes 0..1023)
//   uint  cnt1[s] = u32[256+16s]  (bytes 1024..2047)
//   uint  cnt2[s] = u32[512+16s]  (bytes 2048..3071)       <- memset covers 0..3071
//   u1=wsf[768..831] v1=wsf[832..895] u2=wsf[896..911] v2=wsf[912..927]  (k_pre, no memset)
//   a1 bf16[64][64] @4096,  a2 bf16[16][64] @12288.  need = 16384 B.

// ---- k_pre: weight prep (1 block, 256 thr) ----
__global__ __launch_bounds__(256) void k_pre(
    const float* __restrict__ w1, const float* __restrict__ b1,
    const float* __restrict__ s1, const float* __restrict__ gb1,
    const float* __restrict__ w2, const float* __restrict__ b2,
    const float* __restrict__ s2, const float* __restrict__ gb2,
    float* __restrict__ wsf,
    unsigned short* __restrict__ a1, unsigned short* __restrict__ a2) {
  const int tid = threadIdx.x;
  {
    int o = tid >> 2, q = tid & 3;
    float u = 0.f, v = 0.f;
    unsigned short loc[16];
#pragma unroll
    for (int i = 0; i < 16; ++i) {
      int c = q * 16 + i;
      float wv = w1[o * 64 + c];
      float wsc = wv * s1[c];
      loc[i] = f2bf(wsc);
      u += wsc;
      v += wv * gb1[c];
    }
    *(short8*)(a1 + o * 64 + q * 16) = *(short8*)loc;
    *(short8*)(a1 + o * 64 + q * 16 + 8) = *(short8*)(loc + 8);
    u += __shfl_xor(u, 1, 64); u += __shfl_xor(u, 2, 64);
    v += __shfl_xor(v, 1, 64); v += __shfl_xor(v, 2, 64);
    if (q == 0) { wsf[768 + o] = u; wsf[832 + o] = b1[o] + v; }
  }
  if (tid < 64) {
    int o = tid >> 2, q = tid & 3;
    float u = 0.f, v = 0.f;
    unsigned short loc[16];
#pragma unroll
    for (int i = 0; i < 16; ++i) {
      int c = q * 16 + i;
      float wv = (o < 6) ? w2[o * 64 + c] : 0.f;
      float wsc = wv * s2[c];
      loc[i] = f2bf(wsc);
      u += wsc;
      v += wv * gb2[c];
    }
    *(short8*)(a2 + o * 64 + q * 16) = *(short8*)loc;
    *(short8*)(a2 + o * 64 + q * 16 + 8) = *(short8*)(loc + 8);
    u += __shfl_xor(u, 1, 64); u += __shfl_xor(u, 2, 64);
    v += __shfl_xor(v, 1, 64); v += __shfl_xor(v, 2, 64);
    if (q == 0) { wsf[896 + o] = u; wsf[912 + o] = ((o < 6) ? b2[o] : 0.f) + v; }
  }
}

__device__ __forceinline__ void sample_wait(unsigned* cnt, unsigned target) {
  if (threadIdx.x == 0) {
    unsigned spins = 0;
    while (__hip_atomic_load(cnt, __ATOMIC_RELAXED, __HIP_MEMORY_SCOPE_AGENT) < target) {
      __builtin_amdgcn_s_sleep(8);
      if (++spins > (1u << 18)) break;  // fail bounded, never hang
    }
    (void)__hip_atomic_load(cnt, __ATOMIC_ACQUIRE, __HIP_MEMORY_SCOPE_AGENT);
  }
  __syncthreads();
}

// ---- mega: x (read ONCE) -> stats -> [sample wait] -> conv1 -> silu+hstats
//            -> conv2 (regs) -> [sample wait] -> final affine -> out ----
__global__ __launch_bounds__(256, 4) void mega(const float* __restrict__ x,
                                               const unsigned short* __restrict__ a1,
                                               const unsigned short* __restrict__ a2,
                                               float* __restrict__ wsf,
                                               float* __restrict__ out) {
  __shared__ __align__(16) unsigned char tile[128 * 128];
  __shared__ float red[8];
  unsigned* cnt1 = (unsigned*)wsf + 256;
  unsigned* cnt2 = (unsigned*)wsf + 512;
  const int tid = threadIdx.x;
  const int l = tid & 63, w = tid >> 6;
  const int s = blockIdx.y;
  const int ptile = blockIdx.x * 128;
  const float* xb = x + (size_t)s * CH * HW;

  // ---- phase 1: load tile (regs) + x partial stats ----
  const int c0 = (tid >> 5) * 8;
  const int p4 = (tid & 31) * 4;
  f32x4 v[8];
  const float* base = xb + (size_t)c0 * HW + ptile + p4;
#pragma unroll
  for (int i = 0; i < 8; ++i) v[i] = *(const f32x4*)(base + (size_t)i * HW);

  {
    float ss = 0.f, qq = 0.f;
#pragma unroll
    for (int i = 0; i < 8; ++i)
#pragma unroll
      for (int j = 0; j < 4; ++j) { float f = v[i][j]; ss += f; qq += f * f; }
#pragma unroll
    for (int off = 32; off > 0; off >>= 1) {
      ss += __shfl_down(ss, off, 64);
      qq += __shfl_down(qq, off, 64);
    }
    if (l == 0) { red[w] = ss; red[4 + w] = qq; }
  }
  // convert + transpose into LDS while stats settle
#pragma unroll
  for (int dp = 0; dp < 4; ++dp) {
    int p = p4 + dp;
    short8 w8;
#pragma unroll
    for (int i = 0; i < 8; ++i) w8[i] = cvt1(v[i][dp]);
    *(short8*)(tile + p * 128 + swz(p, c0 >> 3) * 16) = w8;
  }
  __syncthreads();  // red[] ready + transpose complete
  if (tid == 0) {
    atomicAdd(wsf + 16 * s + 0, red[0] + red[1] + red[2] + red[3]);
    atomicAdd(wsf + 16 * s + 1, red[4] + red[5] + red[6] + red[7]);
    __hip_atomic_fetch_add(cnt1 + 16 * s, 1u, __ATOMIC_RELEASE, __HIP_MEMORY_SCOPE_AGENT);
  }

  // weight fragments (L2-hot loads; overlap the wait below)
  bf16x8 af[4][2];
#pragma unroll
  for (int mf = 0; mf < 4; ++mf)
#pragma unroll
    for (int ks = 0; ks < 2; ++ks)
      af[mf][ks] = *(const bf16x8*)((const unsigned char*)a1 +
                     (mf * 16 + (l & 15)) * 128 + ks * 64 + (l >> 4) * 16);
  bf16x8 a2f[2];
#pragma unroll
  for (int ks = 0; ks < 2; ++ks)
    a2f[ks] = *(const bf16x8*)((const unsigned char*)a2 +
                 (l & 15) * 128 + ks * 64 + (l >> 4) * 16);

  sample_wait(cnt1 + 16 * s, 512);

  // per-sample GN1 scalars (stats written by other blocks -> scoped atomic loads)
  const float sumx = __hip_atomic_load(wsf + 16 * s + 0, __ATOMIC_RELAXED, __HIP_MEMORY_SCOPE_AGENT);
  const float sumq = __hip_atomic_load(wsf + 16 * s + 1, __ATOMIC_RELAXED, __HIP_MEMORY_SCOPE_AGENT);
  const float m1 = sumx / NPIXF;
  const float rs1 = rsqrtf(sumq / NPIXF - m1 * m1 + 1e-6f);
  float c1r[4][4];
#pragma unroll
  for (int mf = 0; mf < 4; ++mf) {
    const int o0 = mf * 16 + (l >> 4) * 4;
    f32x4 u = *(const f32x4*)(wsf + 768 + o0);
    f32x4 vv = *(const f32x4*)(wsf + 832 + o0);
#pragma unroll
    for (int r = 0; r < 4; ++r) c1r[mf][r] = vv[r] - rs1 * m1 * u[r];
  }

  // B-fragments from tile (wave-private rows afterwards)
  bf16x8 bfr[2][2];
#pragma unroll
  for (int nf = 0; nf < 2; ++nf) {
    const int pl = w * 32 + nf * 16 + (l & 15);
#pragma unroll
    for (int ks = 0; ks < 2; ++ks) {
      int cc = ks * 4 + (l >> 4);
      bfr[nf][ks] = *(const bf16x8*)(tile + pl * 128 + swz(pl, cc) * 16);
    }
  }

  // ---- phase A: conv1 + silu + h partial stats, h -> tile ----
  float hs = 0.f, hq = 0.f;
#pragma unroll
  for (int nf = 0; nf < 2; ++nf) {
    const int pl = w * 32 + nf * 16 + (l & 15);
#pragma unroll
    for (int mf = 0; mf < 4; ++mf) {
      f32x4 acc = {0.f, 0.f, 0.f, 0.f};
      acc = __builtin_amdgcn_mfma_f32_16x16x32_bf16(af[mf][0], bfr[nf][0], acc, 0, 0, 0);
      acc = __builtin_amdgcn_mfma_f32_16x16x32_bf16(af[mf][1], bfr[nf][1], acc, 0, 0, 0);
      const int o0 = mf * 16 + (l >> 4) * 4;
      short4v hv;
#pragma unroll
      for (int r = 0; r < 4; ++r) {
        float z = rs1 * acc[r] + c1r[mf][r];
        float hh = z * fastrcp(1.f + __expf(-z));
        hs += hh; hq += hh * hh;
        hv[r] = cvt1(hh);
      }
      *(short4v*)(tile + pl * 128 + swz(pl, o0 >> 3) * 16 + (o0 & 7) * 2) = hv;
    }
  }
#pragma unroll
  for (int off = 32; off > 0; off >>= 1) {
    hs += __shfl_down(hs, off, 64);
    hq += __shfl_down(hq, off, 64);
  }
  if (l == 0) { red[w] = hs; red[4 + w] = hq; }
  __syncthreads();
  if (tid == 0) {
    atomicAdd(wsf + 16 * s + 2, red[0] + red[1] + red[2] + red[3]);
    atomicAdd(wsf + 16 * s + 3, red[4] + red[5] + red[6] + red[7]);
    __hip_atomic_fetch_add(cnt2 + 16 * s, 1u, __ATOMIC_RELEASE, __HIP_MEMORY_SCOPE_AGENT);
  }

  // ---- phase B: conv2 into registers (overlaps other blocks finishing) ----
  f32x4 yr[2];
#pragma unroll
  for (int nf = 0; nf < 2; ++nf) {
    const int pl = w * 32 + nf * 16 + (l & 15);
    bf16x8 hfr[2];
#pragma unroll
    for (int ks = 0; ks < 2; ++ks) {
      int cc = ks * 4 + (l >> 4);
      hfr[ks] = *(const bf16x8*)(tile + pl * 128 + swz(pl, cc) * 16);
    }
    f32x4 acc = {0.f, 0.f, 0.f, 0.f};
    acc = __builtin_amdgcn_mfma_f32_16x16x32_bf16(a2f[0], hfr[0], acc, 0, 0, 0);
    acc = __builtin_amdgcn_mfma_f32_16x16x32_bf16(a2f[1], hfr[1], acc, 0, 0, 0);
    yr[nf] = acc;
  }

  sample_wait(cnt2 + 16 * s, 512);

  // ---- phase 3: final affine (GN2 folded) -> out ----
  const float sumh = __hip_atomic_load(wsf + 16 * s + 2, __ATOMIC_RELAXED, __HIP_MEMORY_SCOPE_AGENT);
  const float sumhq = __hip_atomic_load(wsf + 16 * s + 3, __ATOMIC_RELAXED, __HIP_MEMORY_SCOPE_AGENT);
  const float m2 = sumh / NPIXF;
  const float rs2 = rsqrtf(sumhq / NPIXF - m2 * m2 + 1e-6f);
  const int ob0 = (l >> 4) * 4;
  f32x4 u2v = *(const f32x4*)(wsf + 896 + ob0);
  f32x4 v2v = *(const f32x4*)(wsf + 912 + ob0);
  float* ob = out + (size_t)s * 6 * HW;
#pragma unroll
  for (int nf = 0; nf < 2; ++nf) {
    const int p = ptile + w * 32 + nf * 16 + (l & 15);
#pragma unroll
    for (int r = 0; r < 4; ++r) {
      int o = ob0 + r;
      if (o < 6) ob[(size_t)o * HW + p] = rs2 * yr[nf][r] + (v2v[r] - rs2 * m2 * u2v[r]);
    }
  }
}

extern "C" void kernel_launch(void* const* d_in, const int* in_sizes, int n_in,
                              void* d_out, int out_size, void* d_ws, size_t ws_size,
                              hipStream_t stream) {
  const float* x  = (const float*)d_in[0];
  const float* s1 = (const float*)d_in[1];
  const float* g1 = (const float*)d_in[2];
  const float* w1 = (const float*)d_in[3];
  const float* b1 = (const float*)d_in[4];
  const float* s2 = (const float*)d_in[5];
  const float* g2 = (const float*)d_in[6];
  const float* w2 = (const float*)d_in[7];
  const float* b2 = (const float*)d_in[8];
  float* out = (float*)d_out;
  float* wsf = (float*)d_ws;
  unsigned short* a1 = (unsigned short*)((char*)d_ws + 4096);
  unsigned short* a2 = (unsigned short*)((char*)d_ws + 12288);

  if (ws_size < 16384) return;

  hipMemsetAsync(d_ws, 0, 3072, stream);  // stats + cnt1 + cnt2
  k_pre<<<1, 256, 0, stream>>>(w1, b1, s1, g1, w2, b2, s2, g2, wsf, a1, a2);
  mega<<<dim3(512, 16), 256, 0, stream>>>(x, a1, a2, wsf, out);
}

// Round 12
// 242.705 us; speedup vs baseline: 6.3015x; 6.3015x over previous
//
#include <hip/hip_runtime.h>

#define HW 65536
#define CH 64
#define NPIXF 4194304.0f

typedef __attribute__((ext_vector_type(8))) short short8;
typedef __attribute__((ext_vector_type(4))) short short4v;
typedef __attribute__((ext_vector_type(8))) __bf16 bf16x8;
typedef __attribute__((ext_vector_type(4))) float f32x4;

__device__ __forceinline__ unsigned short f2bf(float f) {
  unsigned int u = __builtin_bit_cast(unsigned int, f);
  u += 0x7FFFu + ((u >> 16) & 1u);
  return (unsigned short)(u >> 16);
}
__device__ __forceinline__ short cvt1(float f) {
  return __builtin_bit_cast(short, (__bf16)f);
}
__device__ __forceinline__ float fastrcp(float f) {
  return __builtin_amdgcn_rcpf(f);
}
__device__ __forceinline__ int swz(int p, int cc) { return cc ^ ((p ^ (p >> 3)) & 7); }

// ws layout (floats):
//   stats: wsf[16*s+0]=sum_x +1=sumsq_x +2=sum_h +3=sumsq_h  (64B line/sample, memset-zeroed)
//   consts: u1=wsf[256..319]  v1=wsf[320..383]  u2=wsf[384..399]  v2=wsf[400..415]
//   a1 bf16[64][64] @2048, a2 bf16[16][64] @10240
//   scratch stat lines for diagnostic k2 dup: bytes 12288..13311 (floats 3072..3327)
// need = 16384 B.

// ---- k1: x stats (streaming, full occupancy); block (0,0) preps weights ----
__global__ __launch_bounds__(256, 8) void k1(
    const float* __restrict__ x,
    const float* __restrict__ w1, const float* __restrict__ b1,
    const float* __restrict__ s1, const float* __restrict__ gb1,
    const float* __restrict__ w2, const float* __restrict__ b2,
    const float* __restrict__ s2, const float* __restrict__ gb2,
    float* __restrict__ wsf,
    unsigned short* __restrict__ a1, unsigned short* __restrict__ a2) {
  __shared__ float red[8];
  const int tid = threadIdx.x;
  const int l = tid & 63, w = tid >> 6;
  const int b = blockIdx.y;

  if (blockIdx.x == 0 && b == 0) {
    {
      int o = tid >> 2, q = tid & 3;
      float u = 0.f, v = 0.f;
      unsigned short loc[16];
#pragma unroll
      for (int i = 0; i < 16; ++i) {
        int c = q * 16 + i;
        float wv = w1[o * 64 + c];
        float wsc = wv * s1[c];
        loc[i] = f2bf(wsc);
        u += wsc;
        v += wv * gb1[c];
      }
      *(short8*)(a1 + o * 64 + q * 16) = *(short8*)loc;
      *(short8*)(a1 + o * 64 + q * 16 + 8) = *(short8*)(loc + 8);
      u += __shfl_xor(u, 1, 64); u += __shfl_xor(u, 2, 64);
      v += __shfl_xor(v, 1, 64); v += __shfl_xor(v, 2, 64);
      if (q == 0) { wsf[256 + o] = u; wsf[320 + o] = b1[o] + v; }
    }
    if (tid < 64) {
      int o = tid >> 2, q = tid & 3;
      float u = 0.f, v = 0.f;
      unsigned short loc[16];
#pragma unroll
      for (int i = 0; i < 16; ++i) {
        int c = q * 16 + i;
        float wv = (o < 6) ? w2[o * 64 + c] : 0.f;
        float wsc = wv * s2[c];
        loc[i] = f2bf(wsc);
        u += wsc;
        v += wv * gb2[c];
      }
      *(short8*)(a2 + o * 64 + q * 16) = *(short8*)loc;
      *(short8*)(a2 + o * 64 + q * 16 + 8) = *(short8*)(loc + 8);
      u += __shfl_xor(u, 1, 64); u += __shfl_xor(u, 2, 64);
      v += __shfl_xor(v, 1, 64); v += __shfl_xor(v, 2, 64);
      if (q == 0) { wsf[384 + o] = u; wsf[400 + o] = ((o < 6) ? b2[o] : 0.f) + v; }
    }
  }

  const f32x4* xb = (const f32x4*)(x + (size_t)b * CH * HW);
  const f32x4* p = xb + (size_t)blockIdx.x * 8192 + tid;
  float s = 0.f, q = 0.f;
#pragma unroll
  for (int it = 0; it < 32; ++it) {
    f32x4 v = p[it * 256];
#pragma unroll
    for (int i = 0; i < 4; ++i) { float f = v[i]; s += f; q += f * f; }
  }
#pragma unroll
  for (int off = 32; off > 0; off >>= 1) {
    s += __shfl_down(s, off, 64);
    q += __shfl_down(q, off, 64);
  }
  if (l == 0) { red[w] = s; red[4 + w] = q; }
  __syncthreads();
  if (tid == 0) {
    atomicAdd(wsf + 16 * b + 0, red[0] + red[1] + red[2] + red[3]);
    atomicAdd(wsf + 16 * b + 1, red[4] + red[5] + red[6] + red[7]);
  }
}

// ---- k2: x -> conv1 MFMA -> silu+h-stats -> conv2 -> raw y ----
// rev selects traversal order; wstat selects where h-stat atomics land.
__global__ __launch_bounds__(256, 4) void k2(const float* __restrict__ x,
                                             const unsigned short* __restrict__ a1,
                                             const unsigned short* __restrict__ a2,
                                             const float* __restrict__ wsf,
                                             float* __restrict__ wstat,
                                             float* __restrict__ out,
                                             int rev) {
  __shared__ __align__(16) unsigned char tile[128 * 128];
  __shared__ float red[8];
  const int tid = threadIdx.x;
  const int l = tid & 63, w = tid >> 6;
  const int s = rev ? (15 - blockIdx.y) : blockIdx.y;
  const int ptile = (rev ? (511 - blockIdx.x) : blockIdx.x) * 128;
  const float* xb = x + (size_t)s * CH * HW;

  const float m1 = wsf[16 * s + 0] / NPIXF;
  const float rs1 = rsqrtf(wsf[16 * s + 1] / NPIXF - m1 * m1 + 1e-6f);

  float c1r[4][4];
#pragma unroll
  for (int mf = 0; mf < 4; ++mf) {
    const int o0 = mf * 16 + (l >> 4) * 4;
    f32x4 u = *(const f32x4*)(wsf + 256 + o0);
    f32x4 vv = *(const f32x4*)(wsf + 320 + o0);
#pragma unroll
    for (int r = 0; r < 4; ++r) c1r[mf][r] = vv[r] - rs1 * m1 * u[r];
  }

  bf16x8 af[4][2];
#pragma unroll
  for (int mf = 0; mf < 4; ++mf)
#pragma unroll
    for (int ks = 0; ks < 2; ++ks)
      af[mf][ks] = *(const bf16x8*)((const unsigned char*)a1 +
                     (mf * 16 + (l & 15)) * 128 + ks * 64 + (l >> 4) * 16);
  bf16x8 a2f[2];
#pragma unroll
  for (int ks = 0; ks < 2; ++ks)
    a2f[ks] = *(const bf16x8*)((const unsigned char*)a2 +
                 (l & 15) * 128 + ks * 64 + (l >> 4) * 16);

  const int c0 = (tid >> 5) * 8;
  const int p4 = (tid & 31) * 4;
  f32x4 v[8];
  const float* base = xb + (size_t)c0 * HW + ptile + p4;
#pragma unroll
  for (int i = 0; i < 8; ++i) v[i] = *(const f32x4*)(base + (size_t)i * HW);
#pragma unroll
  for (int dp = 0; dp < 4; ++dp) {
    int p = p4 + dp;
    short8 w8;
#pragma unroll
    for (int i = 0; i < 8; ++i) w8[i] = cvt1(v[i][dp]);
    *(short8*)(tile + p * 128 + swz(p, c0 >> 3) * 16) = w8;
  }
  __syncthreads();  // only barrier: cross-wave transpose complete

  bf16x8 bfr[2][2];
#pragma unroll
  for (int nf = 0; nf < 2; ++nf) {
    const int pl = w * 32 + nf * 16 + (l & 15);
#pragma unroll
    for (int ks = 0; ks < 2; ++ks) {
      int cc = ks * 4 + (l >> 4);
      bfr[nf][ks] = *(const bf16x8*)(tile + pl * 128 + swz(pl, cc) * 16);
    }
  }

  float hs = 0.f, hq = 0.f;
#pragma unroll
  for (int nf = 0; nf < 2; ++nf) {
    const int pl = w * 32 + nf * 16 + (l & 15);
#pragma unroll
    for (int mf = 0; mf < 4; ++mf) {
      f32x4 acc = {0.f, 0.f, 0.f, 0.f};
      acc = __builtin_amdgcn_mfma_f32_16x16x32_bf16(af[mf][0], bfr[nf][0], acc, 0, 0, 0);
      acc = __builtin_amdgcn_mfma_f32_16x16x32_bf16(af[mf][1], bfr[nf][1], acc, 0, 0, 0);
      const int o0 = mf * 16 + (l >> 4) * 4;
      short4v hv;
#pragma unroll
      for (int r = 0; r < 4; ++r) {
        float z = rs1 * acc[r] + c1r[mf][r];
        float hh = z * fastrcp(1.f + __expf(-z));
        hs += hh; hq += hh * hh;
        hv[r] = cvt1(hh);
      }
      *(short4v*)(tile + pl * 128 + swz(pl, o0 >> 3) * 16 + (o0 & 7) * 2) = hv;
    }
  }

  float* ob = out + (size_t)s * 6 * HW;
#pragma unroll
  for (int nf = 0; nf < 2; ++nf) {
    const int pl = w * 32 + nf * 16 + (l & 15);
    const int p = ptile + pl;
    bf16x8 hfr[2];
#pragma unroll
    for (int ks = 0; ks < 2; ++ks) {
      int cc = ks * 4 + (l >> 4);
      hfr[ks] = *(const bf16x8*)(tile + pl * 128 + swz(pl, cc) * 16);
    }
    f32x4 acc = {0.f, 0.f, 0.f, 0.f};
    acc = __builtin_amdgcn_mfma_f32_16x16x32_bf16(a2f[0], hfr[0], acc, 0, 0, 0);
    acc = __builtin_amdgcn_mfma_f32_16x16x32_bf16(a2f[1], hfr[1], acc, 0, 0, 0);
    const int ob0 = (l >> 4) * 4;
#pragma unroll
    for (int r = 0; r < 4; ++r) {
      int o = ob0 + r;
      if (o < 6) ob[(size_t)o * HW + p] = acc[r];
    }
  }

#pragma unroll
  for (int off = 32; off > 0; off >>= 1) {
    hs += __shfl_down(hs, off, 64);
    hq += __shfl_down(hq, off, 64);
  }
  if (l == 0) { red[w] = hs; red[4 + w] = hq; }
  __syncthreads();
  if (tid == 0) {
    atomicAdd(wstat + 16 * s + 2, red[0] + red[1] + red[2] + red[3]);
    atomicAdd(wstat + 16 * s + 3, red[4] + red[5] + red[6] + red[7]);
  }
}

// ---- k3: out = rs2*out + c2[o]  (in-place, elementwise; reverse order) ----
__global__ __launch_bounds__(256) void k3(float* __restrict__ out,
                                          const float* __restrict__ wsf) {
  const int s = 15 - blockIdx.y;
  const float m2 = wsf[16 * s + 2] / NPIXF;
  const float rs2 = rsqrtf(wsf[16 * s + 3] / NPIXF - m2 * m2 + 1e-6f);
  float* ob = out + (size_t)s * 6 * HW;
#pragma unroll
  for (int it = 0; it < 4; ++it) {
    int f4 = blockIdx.x * 256 + threadIdx.x + it * 24576;  // < 98304
    int o = f4 >> 14;
    float c2 = wsf[400 + o] - rs2 * m2 * wsf[384 + o];
    f32x4* p = (f32x4*)ob + f4;
    f32x4 v = *p;
#pragma unroll
    for (int i = 0; i < 4; ++i) v[i] = rs2 * v[i] + c2;
    *p = v;
  }
}

extern "C" void kernel_launch(void* const* d_in, const int* in_sizes, int n_in,
                              void* d_out, int out_size, void* d_ws, size_t ws_size,
                              hipStream_t stream) {
  const float* x  = (const float*)d_in[0];
  const float* s1 = (const float*)d_in[1];
  const float* g1 = (const float*)d_in[2];
  const float* w1 = (const float*)d_in[3];
  const float* b1 = (const float*)d_in[4];
  const float* s2 = (const float*)d_in[5];
  const float* g2 = (const float*)d_in[6];
  const float* w2 = (const float*)d_in[7];
  const float* b2 = (const float*)d_in[8];
  float* out = (float*)d_out;
  float* wsf = (float*)d_ws;
  unsigned short* a1 = (unsigned short*)((char*)d_ws + 2048);
  unsigned short* a2 = (unsigned short*)((char*)d_ws + 10240);
  float* wscratch = (float*)((char*)d_ws + 12288);  // dup-k2 h-stat sink (never read)

  if (ws_size < 16384) return;

  hipMemsetAsync(d_ws, 0, 1024, stream);  // zero per-sample stat lines
  k1<<<dim3(128, 16), 256, 0, stream>>>(x, w1, b1, s1, g1, w2, b2, s2, g2, wsf, a1, a2);
  k2<<<dim3(512, 16), 256, 0, stream>>>(x, a1, a2, wsf, wsf, out, 1);       // real
  k2<<<dim3(512, 16), 256, 0, stream>>>(x, a1, a2, wsf, wscratch, out, 0);  // DIAGNOSTIC duplicate
  k3<<<dim3(96, 16), 256, 0, stream>>>(out, wsf);
}

// Round 13
// 188.962 us; speedup vs baseline: 8.0937x; 1.2844x over previous
//
#include <hip/hip_runtime.h>

#define HW 65536
#define CH 64
#define NPIXF 4194304.0f

typedef __attribute__((ext_vector_type(8))) short short8;
typedef __attribute__((ext_vector_type(4))) short short4v;
typedef __attribute__((ext_vector_type(8))) __bf16 bf16x8;
typedef __attribute__((ext_vector_type(4))) float f32x4;

__device__ __forceinline__ unsigned short f2bf(float f) {
  unsigned int u = __builtin_bit_cast(unsigned int, f);
  u += 0x7FFFu + ((u >> 16) & 1u);
  return (unsigned short)(u >> 16);
}
__device__ __forceinline__ short cvt1(float f) {
  return __builtin_bit_cast(short, (__bf16)f);
}
__device__ __forceinline__ float fastrcp(float f) {
  return __builtin_amdgcn_rcpf(f);
}
__device__ __forceinline__ int swz(int p, int cc) { return cc ^ ((p ^ (p >> 3)) & 7); }

// ws layout (floats):
//   stats: wsf[16*s+0]=sum_x +1=sumsq_x +2=sum_h +3=sumsq_h  (64B line/sample, memset-zeroed)
//   consts: u1=wsf[256..319]  v1=wsf[320..383]  u2=wsf[384..399]  v2=wsf[400..415]
//   a1 bf16[64][64] @2048, a2 bf16[16][64] @10240.  need = 16384 B.

// ---- k1: x stats for samples [b0, b0+8); block (0,0) of chunk 0 preps weights ----
__global__ __launch_bounds__(256, 8) void k1(
    const float* __restrict__ x,
    const float* __restrict__ w1, const float* __restrict__ b1,
    const float* __restrict__ s1, const float* __restrict__ gb1,
    const float* __restrict__ w2, const float* __restrict__ b2,
    const float* __restrict__ s2, const float* __restrict__ gb2,
    float* __restrict__ wsf,
    unsigned short* __restrict__ a1, unsigned short* __restrict__ a2,
    int b0) {
  __shared__ float red[8];
  const int tid = threadIdx.x;
  const int l = tid & 63, w = tid >> 6;
  const int b = b0 + blockIdx.y;

  if (blockIdx.x == 0 && blockIdx.y == 0 && b0 == 0) {
    {
      int o = tid >> 2, q = tid & 3;
      float u = 0.f, v = 0.f;
      unsigned short loc[16];
#pragma unroll
      for (int i = 0; i < 16; ++i) {
        int c = q * 16 + i;
        float wv = w1[o * 64 + c];
        float wsc = wv * s1[c];
        loc[i] = f2bf(wsc);
        u += wsc;
        v += wv * gb1[c];
      }
      *(short8*)(a1 + o * 64 + q * 16) = *(short8*)loc;
      *(short8*)(a1 + o * 64 + q * 16 + 8) = *(short8*)(loc + 8);
      u += __shfl_xor(u, 1, 64); u += __shfl_xor(u, 2, 64);
      v += __shfl_xor(v, 1, 64); v += __shfl_xor(v, 2, 64);
      if (q == 0) { wsf[256 + o] = u; wsf[320 + o] = b1[o] + v; }
    }
    if (tid < 64) {
      int o = tid >> 2, q = tid & 3;
      float u = 0.f, v = 0.f;
      unsigned short loc[16];
#pragma unroll
      for (int i = 0; i < 16; ++i) {
        int c = q * 16 + i;
        float wv = (o < 6) ? w2[o * 64 + c] : 0.f;
        float wsc = wv * s2[c];
        loc[i] = f2bf(wsc);
        u += wsc;
        v += wv * gb2[c];
      }
      *(short8*)(a2 + o * 64 + q * 16) = *(short8*)loc;
      *(short8*)(a2 + o * 64 + q * 16 + 8) = *(short8*)(loc + 8);
      u += __shfl_xor(u, 1, 64); u += __shfl_xor(u, 2, 64);
      v += __shfl_xor(v, 1, 64); v += __shfl_xor(v, 2, 64);
      if (q == 0) { wsf[384 + o] = u; wsf[400 + o] = ((o < 6) ? b2[o] : 0.f) + v; }
    }
  }

  const f32x4* xb = (const f32x4*)(x + (size_t)b * CH * HW);
  const f32x4* p = xb + (size_t)blockIdx.x * 8192 + tid;
  float s = 0.f, q = 0.f;
#pragma unroll
  for (int it = 0; it < 32; ++it) {
    f32x4 v = p[it * 256];
#pragma unroll
    for (int i = 0; i < 4; ++i) { float f = v[i]; s += f; q += f * f; }
  }
#pragma unroll
  for (int off = 32; off > 0; off >>= 1) {
    s += __shfl_down(s, off, 64);
    q += __shfl_down(q, off, 64);
  }
  if (l == 0) { red[w] = s; red[4 + w] = q; }
  __syncthreads();
  if (tid == 0) {
    atomicAdd(wsf + 16 * b + 0, red[0] + red[1] + red[2] + red[3]);
    atomicAdd(wsf + 16 * b + 1, red[4] + red[5] + red[6] + red[7]);
  }
}

// ---- k2: samples [b0, b0+8) (L3-hot from the k1 chunk just before) ----
__global__ __launch_bounds__(256, 4) void k2(const float* __restrict__ x,
                                             const unsigned short* __restrict__ a1,
                                             const unsigned short* __restrict__ a2,
                                             const float* __restrict__ wsf,
                                             float* __restrict__ wstat,
                                             float* __restrict__ out,
                                             int b0) {
  __shared__ __align__(16) unsigned char tile[128 * 128];
  __shared__ float red[8];
  const int tid = threadIdx.x;
  const int l = tid & 63, w = tid >> 6;
  const int s = b0 + 7 - blockIdx.y;             // reverse within chunk
  const int ptile = (511 - blockIdx.x) * 128;
  const float* xb = x + (size_t)s * CH * HW;

  const float m1 = wsf[16 * s + 0] / NPIXF;
  const float rs1 = rsqrtf(wsf[16 * s + 1] / NPIXF - m1 * m1 + 1e-6f);

  float c1r[4][4];
#pragma unroll
  for (int mf = 0; mf < 4; ++mf) {
    const int o0 = mf * 16 + (l >> 4) * 4;
    f32x4 u = *(const f32x4*)(wsf + 256 + o0);
    f32x4 vv = *(const f32x4*)(wsf + 320 + o0);
#pragma unroll
    for (int r = 0; r < 4; ++r) c1r[mf][r] = vv[r] - rs1 * m1 * u[r];
  }

  bf16x8 af[4][2];
#pragma unroll
  for (int mf = 0; mf < 4; ++mf)
#pragma unroll
    for (int ks = 0; ks < 2; ++ks)
      af[mf][ks] = *(const bf16x8*)((const unsigned char*)a1 +
                     (mf * 16 + (l & 15)) * 128 + ks * 64 + (l >> 4) * 16);
  bf16x8 a2f[2];
#pragma unroll
  for (int ks = 0; ks < 2; ++ks)
    a2f[ks] = *(const bf16x8*)((const unsigned char*)a2 +
                 (l & 15) * 128 + ks * 64 + (l >> 4) * 16);

  const int c0 = (tid >> 5) * 8;
  const int p4 = (tid & 31) * 4;
  f32x4 v[8];
  const float* base = xb + (size_t)c0 * HW + ptile + p4;
#pragma unroll
  for (int i = 0; i < 8; ++i) v[i] = *(const f32x4*)(base + (size_t)i * HW);
#pragma unroll
  for (int dp = 0; dp < 4; ++dp) {
    int p = p4 + dp;
    short8 w8;
#pragma unroll
    for (int i = 0; i < 8; ++i) w8[i] = cvt1(v[i][dp]);
    *(short8*)(tile + p * 128 + swz(p, c0 >> 3) * 16) = w8;
  }
  __syncthreads();  // only barrier: cross-wave transpose complete

  bf16x8 bfr[2][2];
#pragma unroll
  for (int nf = 0; nf < 2; ++nf) {
    const int pl = w * 32 + nf * 16 + (l & 15);
#pragma unroll
    for (int ks = 0; ks < 2; ++ks) {
      int cc = ks * 4 + (l >> 4);
      bfr[nf][ks] = *(const bf16x8*)(tile + pl * 128 + swz(pl, cc) * 16);
    }
  }

  float hs = 0.f, hq = 0.f;
#pragma unroll
  for (int nf = 0; nf < 2; ++nf) {
    const int pl = w * 32 + nf * 16 + (l & 15);
#pragma unroll
    for (int mf = 0; mf < 4; ++mf) {
      f32x4 acc = {0.f, 0.f, 0.f, 0.f};
      acc = __builtin_amdgcn_mfma_f32_16x16x32_bf16(af[mf][0], bfr[nf][0], acc, 0, 0, 0);
      acc = __builtin_amdgcn_mfma_f32_16x16x32_bf16(af[mf][1], bfr[nf][1], acc, 0, 0, 0);
      const int o0 = mf * 16 + (l >> 4) * 4;
      short4v hv;
#pragma unroll
      for (int r = 0; r < 4; ++r) {
        float z = rs1 * acc[r] + c1r[mf][r];
        float hh = z * fastrcp(1.f + __expf(-z));
        hs += hh; hq += hh * hh;
        hv[r] = cvt1(hh);
      }
      *(short4v*)(tile + pl * 128 + swz(pl, o0 >> 3) * 16 + (o0 & 7) * 2) = hv;
    }
  }

  float* ob = out + (size_t)s * 6 * HW;
#pragma unroll
  for (int nf = 0; nf < 2; ++nf) {
    const int pl = w * 32 + nf * 16 + (l & 15);
    const int p = ptile + pl;
    bf16x8 hfr[2];
#pragma unroll
    for (int ks = 0; ks < 2; ++ks) {
      int cc = ks * 4 + (l >> 4);
      hfr[ks] = *(const bf16x8*)(tile + pl * 128 + swz(pl, cc) * 16);
    }
    f32x4 acc = {0.f, 0.f, 0.f, 0.f};
    acc = __builtin_amdgcn_mfma_f32_16x16x32_bf16(a2f[0], hfr[0], acc, 0, 0, 0);
    acc = __builtin_amdgcn_mfma_f32_16x16x32_bf16(a2f[1], hfr[1], acc, 0, 0, 0);
    const int ob0 = (l >> 4) * 4;
#pragma unroll
    for (int r = 0; r < 4; ++r) {
      int o = ob0 + r;
      if (o < 6) ob[(size_t)o * HW + p] = acc[r];
    }
  }

#pragma unroll
  for (int off = 32; off > 0; off >>= 1) {
    hs += __shfl_down(hs, off, 64);
    hq += __shfl_down(hq, off, 64);
  }
  if (l == 0) { red[w] = hs; red[4 + w] = hq; }
  __syncthreads();
  if (tid == 0) {
    atomicAdd(wstat + 16 * s + 2, red[0] + red[1] + red[2] + red[3]);
    atomicAdd(wstat + 16 * s + 3, red[4] + red[5] + red[6] + red[7]);
  }
}

// ---- k3: out = rs2*out + c2[o]  (in-place, elementwise) ----
__global__ __launch_bounds__(256) void k3(float* __restrict__ out,
                                          const float* __restrict__ wsf) {
  const int s = 15 - blockIdx.y;
  const float m2 = wsf[16 * s + 2] / NPIXF;
  const float rs2 = rsqrtf(wsf[16 * s + 3] / NPIXF - m2 * m2 + 1e-6f);
  float* ob = out + (size_t)s * 6 * HW;
#pragma unroll
  for (int it = 0; it < 4; ++it) {
    int f4 = blockIdx.x * 256 + threadIdx.x + it * 24576;  // < 98304
    int o = f4 >> 14;
    float c2 = wsf[400 + o] - rs2 * m2 * wsf[384 + o];
    f32x4* p = (f32x4*)ob + f4;
    f32x4 v = *p;
#pragma unroll
    for (int i = 0; i < 4; ++i) v[i] = rs2 * v[i] + c2;
    *p = v;
  }
}

extern "C" void kernel_launch(void* const* d_in, const int* in_sizes, int n_in,
                              void* d_out, int out_size, void* d_ws, size_t ws_size,
                              hipStream_t stream) {
  const float* x  = (const float*)d_in[0];
  const float* s1 = (const float*)d_in[1];
  const float* g1 = (const float*)d_in[2];
  const float* w1 = (const float*)d_in[3];
  const float* b1 = (const float*)d_in[4];
  const float* s2 = (const float*)d_in[5];
  const float* g2 = (const float*)d_in[6];
  const float* w2 = (const float*)d_in[7];
  const float* b2 = (const float*)d_in[8];
  float* out = (float*)d_out;
  float* wsf = (float*)d_ws;
  unsigned short* a1 = (unsigned short*)((char*)d_ws + 2048);
  unsigned short* a2 = (unsigned short*)((char*)d_ws + 10240);

  if (ws_size < 16384) return;

  hipMemsetAsync(d_ws, 0, 1024, stream);  // zero per-sample stat lines
  // chunked: k1(g) streams 8 samples (134 MB, fits L3) then k2(g) re-reads them L3-hot
  k1<<<dim3(128, 8), 256, 0, stream>>>(x, w1, b1, s1, g1, w2, b2, s2, g2, wsf, a1, a2, 0);
  k2<<<dim3(512, 8), 256, 0, stream>>>(x, a1, a2, wsf, wsf, out, 0);
  k1<<<dim3(128, 8), 256, 0, stream>>>(x, w1, b1, s1, g1, w2, b2, s2, g2, wsf, a1, a2, 8);
  k2<<<dim3(512, 8), 256, 0, stream>>>(x, a1, a2, wsf, wsf, out, 8);
  k3<<<dim3(96, 16), 256, 0, stream>>>(out, wsf);
}

// Round 14
// 148.894 us; speedup vs baseline: 10.2717x; 1.2691x over previous
//
#include <hip/hip_runtime.h>

#define HW 65536
#define CH 64
#define NPIXF 4194304.0f

typedef __attribute__((ext_vector_type(8))) short short8;
typedef __attribute__((ext_vector_type(4))) short short4v;
typedef __attribute__((ext_vector_type(8))) __bf16 bf16x8;
typedef __attribute__((ext_vector_type(4))) float f32x4;

__device__ __forceinline__ unsigned short f2bf(float f) {
  unsigned int u = __builtin_bit_cast(unsigned int, f);
  u += 0x7FFFu + ((u >> 16) & 1u);
  return (unsigned short)(u >> 16);
}
__device__ __forceinline__ short cvt1(float f) {
  return __builtin_bit_cast(short, (__bf16)f);
}
__device__ __forceinline__ float fastrcp(float f) {
  return __builtin_amdgcn_rcpf(f);
}
__device__ __forceinline__ int swz(int p, int cc) { return cc ^ ((p ^ (p >> 3)) & 7); }

// ws layout (floats):
//   stats: wsf[16*s+0]=sum_x +1=sumsq_x +2=sum_h +3=sumsq_h  (64B line/sample, memset-zeroed)
//   consts: u1=wsf[256..319]  v1=wsf[320..383]  u2=wsf[384..399]  v2=wsf[400..415]
//   a1 bf16[64][64] @2048, a2 bf16[16][64] @10240.  need = 16384 B.

// ---- k1: x stats (streaming, full occupancy); block (0,0) preps weights ----
__global__ __launch_bounds__(256, 8) void k1(
    const float* __restrict__ x,
    const float* __restrict__ w1, const float* __restrict__ b1,
    const float* __restrict__ s1, const float* __restrict__ gb1,
    const float* __restrict__ w2, const float* __restrict__ b2,
    const float* __restrict__ s2, const float* __restrict__ gb2,
    float* __restrict__ wsf,
    unsigned short* __restrict__ a1, unsigned short* __restrict__ a2) {
  __shared__ float red[8];
  const int tid = threadIdx.x;
  const int l = tid & 63, w = tid >> 6;
  const int b = blockIdx.y;

  if (blockIdx.x == 0 && b == 0) {
    {
      int o = tid >> 2, q = tid & 3;
      float u = 0.f, v = 0.f;
      unsigned short loc[16];
#pragma unroll
      for (int i = 0; i < 16; ++i) {
        int c = q * 16 + i;
        float wv = w1[o * 64 + c];
        float wsc = wv * s1[c];
        loc[i] = f2bf(wsc);
        u += wsc;
        v += wv * gb1[c];
      }
      *(short8*)(a1 + o * 64 + q * 16) = *(short8*)loc;
      *(short8*)(a1 + o * 64 + q * 16 + 8) = *(short8*)(loc + 8);
      u += __shfl_xor(u, 1, 64); u += __shfl_xor(u, 2, 64);
      v += __shfl_xor(v, 1, 64); v += __shfl_xor(v, 2, 64);
      if (q == 0) { wsf[256 + o] = u; wsf[320 + o] = b1[o] + v; }
    }
    if (tid < 64) {
      int o = tid >> 2, q = tid & 3;
      float u = 0.f, v = 0.f;
      unsigned short loc[16];
#pragma unroll
      for (int i = 0; i < 16; ++i) {
        int c = q * 16 + i;
        float wv = (o < 6) ? w2[o * 64 + c] : 0.f;
        float wsc = wv * s2[c];
        loc[i] = f2bf(wsc);
        u += wsc;
        v += wv * gb2[c];
      }
      *(short8*)(a2 + o * 64 + q * 16) = *(short8*)loc;
      *(short8*)(a2 + o * 64 + q * 16 + 8) = *(short8*)(loc + 8);
      u += __shfl_xor(u, 1, 64); u += __shfl_xor(u, 2, 64);
      v += __shfl_xor(v, 1, 64); v += __shfl_xor(v, 2, 64);
      if (q == 0) { wsf[384 + o] = u; wsf[400 + o] = ((o < 6) ? b2[o] : 0.f) + v; }
    }
  }

  const f32x4* xb = (const f32x4*)(x + (size_t)b * CH * HW);
  const f32x4* p = xb + (size_t)blockIdx.x * 8192 + tid;
  float s = 0.f, q = 0.f;
#pragma unroll
  for (int it = 0; it < 32; ++it) {
    f32x4 v = p[it * 256];
#pragma unroll
    for (int i = 0; i < 4; ++i) { float f = v[i]; s += f; q += f * f; }
  }
#pragma unroll
  for (int off = 32; off > 0; off >>= 1) {
    s += __shfl_down(s, off, 64);
    q += __shfl_down(q, off, 64);
  }
  if (l == 0) { red[w] = s; red[4 + w] = q; }
  __syncthreads();
  if (tid == 0) {
    atomicAdd(wsf + 16 * b + 0, red[0] + red[1] + red[2] + red[3]);
    atomicAdd(wsf + 16 * b + 1, red[4] + red[5] + red[6] + red[7]);
  }
}

// ---- k2: fat blocks (512 px), reg->LDS double-buffered pipeline ----
// per subtile j: loads(j+1) issued BEFORE compute(j) -> HBM latency hides under MFMA/silu.
__global__ __launch_bounds__(256, 3) void k2(const float* __restrict__ x,
                                             const unsigned short* __restrict__ a1,
                                             const unsigned short* __restrict__ a2,
                                             const float* __restrict__ wsf,
                                             float* __restrict__ wstat,
                                             float* __restrict__ out) {
  __shared__ __align__(16) unsigned char buf[2][128 * 128];
  __shared__ float red[8];
  const int tid = threadIdx.x;
  const int l = tid & 63, w = tid >> 6;
  const int s = 15 - blockIdx.y;                  // reverse sample order
  const int pbase = (127 - blockIdx.x) * 512;     // 512 px per block, reverse
  const float* xb = x + (size_t)s * CH * HW;

  const float m1 = wsf[16 * s + 0] / NPIXF;
  const float rs1 = rsqrtf(wsf[16 * s + 1] / NPIXF - m1 * m1 + 1e-6f);

  float c1r[4][4];
#pragma unroll
  for (int mf = 0; mf < 4; ++mf) {
    const int o0 = mf * 16 + (l >> 4) * 4;
    f32x4 u = *(const f32x4*)(wsf + 256 + o0);
    f32x4 vv = *(const f32x4*)(wsf + 320 + o0);
#pragma unroll
    for (int r = 0; r < 4; ++r) c1r[mf][r] = vv[r] - rs1 * m1 * u[r];
  }

  bf16x8 af[4][2];
#pragma unroll
  for (int mf = 0; mf < 4; ++mf)
#pragma unroll
    for (int ks = 0; ks < 2; ++ks)
      af[mf][ks] = *(const bf16x8*)((const unsigned char*)a1 +
                     (mf * 16 + (l & 15)) * 128 + ks * 64 + (l >> 4) * 16);
  bf16x8 a2f[2];
#pragma unroll
  for (int ks = 0; ks < 2; ++ks)
    a2f[ks] = *(const bf16x8*)((const unsigned char*)a2 +
                 (l & 15) * 128 + ks * 64 + (l >> 4) * 16);

  const int c0 = (tid >> 5) * 8;
  const int p4 = (tid & 31) * 4;
  const float* base = xb + (size_t)c0 * HW + pbase + p4;
  float* ob = out + (size_t)s * 6 * HW;

  // prologue: load + stage subtile 0 into buf[0]
  f32x4 v[8];
#pragma unroll
  for (int i = 0; i < 8; ++i) v[i] = *(const f32x4*)(base + (size_t)i * HW);
#pragma unroll
  for (int dp = 0; dp < 4; ++dp) {
    int p = p4 + dp;
    short8 w8;
#pragma unroll
    for (int i = 0; i < 8; ++i) w8[i] = cvt1(v[i][dp]);
    *(short8*)(buf[0] + p * 128 + swz(p, c0 >> 3) * 16) = w8;
  }
  __syncthreads();

  float hs = 0.f, hq = 0.f;
#pragma unroll
  for (int j = 0; j < 4; ++j) {
    const int cur = j & 1;
    const int pt = pbase + j * 128;

    // issue next subtile's loads NOW (used only in the stage step below ->
    // compiler defers the waitcnt; loads fly under this subtile's compute)
    if (j < 3) {
#pragma unroll
      for (int i = 0; i < 8; ++i)
        v[i] = *(const f32x4*)(base + (size_t)i * HW + (j + 1) * 128);
    }

    // B-fragments for this subtile
    bf16x8 bfr[2][2];
#pragma unroll
    for (int nf = 0; nf < 2; ++nf) {
      const int pl = w * 32 + nf * 16 + (l & 15);
#pragma unroll
      for (int ks = 0; ks < 2; ++ks) {
        int cc = ks * 4 + (l >> 4);
        bfr[nf][ks] = *(const bf16x8*)(buf[cur] + pl * 128 + swz(pl, cc) * 16);
      }
    }

    // phase A: conv1 + silu + h-stats, h -> buf[cur] in place (wave-private rows)
#pragma unroll
    for (int nf = 0; nf < 2; ++nf) {
      const int pl = w * 32 + nf * 16 + (l & 15);
#pragma unroll
      for (int mf = 0; mf < 4; ++mf) {
        f32x4 acc = {0.f, 0.f, 0.f, 0.f};
        acc = __builtin_amdgcn_mfma_f32_16x16x32_bf16(af[mf][0], bfr[nf][0], acc, 0, 0, 0);
        acc = __builtin_amdgcn_mfma_f32_16x16x32_bf16(af[mf][1], bfr[nf][1], acc, 0, 0, 0);
        const int o0 = mf * 16 + (l >> 4) * 4;
        short4v hv;
#pragma unroll
        for (int r = 0; r < 4; ++r) {
          float z = rs1 * acc[r] + c1r[mf][r];
          float hh = z * fastrcp(1.f + __expf(-z));
          hs += hh; hq += hh * hh;
          hv[r] = cvt1(hh);
        }
        *(short4v*)(buf[cur] + pl * 128 + swz(pl, o0 >> 3) * 16 + (o0 & 7) * 2) = hv;
      }
    }

    // phase B: conv2 -> raw y
#pragma unroll
    for (int nf = 0; nf < 2; ++nf) {
      const int pl = w * 32 + nf * 16 + (l & 15);
      bf16x8 hfr[2];
#pragma unroll
      for (int ks = 0; ks < 2; ++ks) {
        int cc = ks * 4 + (l >> 4);
        hfr[ks] = *(const bf16x8*)(buf[cur] + pl * 128 + swz(pl, cc) * 16);
      }
      f32x4 acc = {0.f, 0.f, 0.f, 0.f};
      acc = __builtin_amdgcn_mfma_f32_16x16x32_bf16(a2f[0], hfr[0], acc, 0, 0, 0);
      acc = __builtin_amdgcn_mfma_f32_16x16x32_bf16(a2f[1], hfr[1], acc, 0, 0, 0);
      const int ob0 = (l >> 4) * 4;
#pragma unroll
      for (int r = 0; r < 4; ++r) {
        int o = ob0 + r;
        if (o < 6) ob[(size_t)o * HW + pt + pl] = acc[r];
      }
    }

    // stage next subtile into the other buffer, then one barrier
    if (j < 3) {
#pragma unroll
      for (int dp = 0; dp < 4; ++dp) {
        int p = p4 + dp;
        short8 w8;
#pragma unroll
        for (int i = 0; i < 8; ++i) w8[i] = cvt1(v[i][dp]);
        *(short8*)(buf[cur ^ 1] + p * 128 + swz(p, c0 >> 3) * 16) = w8;
      }
      __syncthreads();
    }
  }

#pragma unroll
  for (int off = 32; off > 0; off >>= 1) {
    hs += __shfl_down(hs, off, 64);
    hq += __shfl_down(hq, off, 64);
  }
  if (l == 0) { red[w] = hs; red[4 + w] = hq; }
  __syncthreads();
  if (tid == 0) {
    atomicAdd(wstat + 16 * s + 2, red[0] + red[1] + red[2] + red[3]);
    atomicAdd(wstat + 16 * s + 3, red[4] + red[5] + red[6] + red[7]);
  }
}

// ---- k3: out = rs2*out + c2[o]  (in-place, elementwise) ----
__global__ __launch_bounds__(256) void k3(float* __restrict__ out,
                                          const float* __restrict__ wsf) {
  const int s = 15 - blockIdx.y;
  const float m2 = wsf[16 * s + 2] / NPIXF;
  const float rs2 = rsqrtf(wsf[16 * s + 3] / NPIXF - m2 * m2 + 1e-6f);
  float* ob = out + (size_t)s * 6 * HW;
#pragma unroll
  for (int it = 0; it < 4; ++it) {
    int f4 = blockIdx.x * 256 + threadIdx.x + it * 24576;  // < 98304
    int o = f4 >> 14;
    float c2 = wsf[400 + o] - rs2 * m2 * wsf[384 + o];
    f32x4* p = (f32x4*)ob + f4;
    f32x4 v = *p;
#pragma unroll
    for (int i = 0; i < 4; ++i) v[i] = rs2 * v[i] + c2;
    *p = v;
  }
}

extern "C" void kernel_launch(void* const* d_in, const int* in_sizes, int n_in,
                              void* d_out, int out_size, void* d_ws, size_t ws_size,
                              hipStream_t stream) {
  const float* x  = (const float*)d_in[0];
  const float* s1 = (const float*)d_in[1];
  const float* g1 = (const float*)d_in[2];
  const float* w1 = (const float*)d_in[3];
  const float* b1 = (const float*)d_in[4];
  const float* s2 = (const float*)d_in[5];
  const float* g2 = (const float*)d_in[6];
  const float* w2 = (const float*)d_in[7];
  const float* b2 = (const float*)d_in[8];
  float* out = (float*)d_out;
  float* wsf = (float*)d_ws;
  unsigned short* a1 = (unsigned short*)((char*)d_ws + 2048);
  unsigned short* a2 = (unsigned short*)((char*)d_ws + 10240);

  if (ws_size < 16384) return;

  hipMemsetAsync(d_ws, 0, 1024, stream);  // zero per-sample stat lines
  k1<<<dim3(128, 16), 256, 0, stream>>>(x, w1, b1, s1, g1, w2, b2, s2, g2, wsf, a1, a2);
  k2<<<dim3(128, 16), 256, 0, stream>>>(x, a1, a2, wsf, wsf, out);
  k3<<<dim3(96, 16), 256, 0, stream>>>(out, wsf);
}

// Round 15
// 147.586 us; speedup vs baseline: 10.3628x; 1.0089x over previous
//
#include <hip/hip_runtime.h>

#define HW 65536
#define CH 64
#define NPIXF 4194304.0f

typedef __attribute__((ext_vector_type(8))) short short8;
typedef __attribute__((ext_vector_type(4))) short short4v;
typedef __attribute__((ext_vector_type(8))) __bf16 bf16x8;
typedef __attribute__((ext_vector_type(4))) float f32x4;

__device__ __forceinline__ unsigned short f2bf(float f) {
  unsigned int u = __builtin_bit_cast(unsigned int, f);
  u += 0x7FFFu + ((u >> 16) & 1u);
  return (unsigned short)(u >> 16);
}
__device__ __forceinline__ short cvt1(float f) {
  return __builtin_bit_cast(short, (__bf16)f);
}
__device__ __forceinline__ float fastrcp(float f) {
  return __builtin_amdgcn_rcpf(f);
}
__device__ __forceinline__ int swz(int p, int cc) { return cc ^ ((p ^ (p >> 3)) & 7); }

// ws layout (floats):
//   stats: wsf[16*s+0]=sum_x +1=sumsq_x +2=sum_h +3=sumsq_h  (64B line/sample, memset-zeroed)
//   consts: u1=wsf[256..319]  v1=wsf[320..383]  u2=wsf[384..399]  v2=wsf[400..415]
//   a1 bf16[64][64] @2048, a2 bf16[16][64] @10240.  need = 16384 B.

// ---- k1: x stats (streaming, full occupancy); block (0,0) preps weights ----
__global__ __launch_bounds__(256, 8) void k1(
    const float* __restrict__ x,
    const float* __restrict__ w1, const float* __restrict__ b1,
    const float* __restrict__ s1, const float* __restrict__ gb1,
    const float* __restrict__ w2, const float* __restrict__ b2,
    const float* __restrict__ s2, const float* __restrict__ gb2,
    float* __restrict__ wsf,
    unsigned short* __restrict__ a1, unsigned short* __restrict__ a2) {
  __shared__ float red[8];
  const int tid = threadIdx.x;
  const int l = tid & 63, w = tid >> 6;
  const int b = blockIdx.y;

  if (blockIdx.x == 0 && b == 0) {
    {
      int o = tid >> 2, q = tid & 3;
      float u = 0.f, v = 0.f;
      unsigned short loc[16];
#pragma unroll
      for (int i = 0; i < 16; ++i) {
        int c = q * 16 + i;
        float wv = w1[o * 64 + c];
        float wsc = wv * s1[c];
        loc[i] = f2bf(wsc);
        u += wsc;
        v += wv * gb1[c];
      }
      *(short8*)(a1 + o * 64 + q * 16) = *(short8*)loc;
      *(short8*)(a1 + o * 64 + q * 16 + 8) = *(short8*)(loc + 8);
      u += __shfl_xor(u, 1, 64); u += __shfl_xor(u, 2, 64);
      v += __shfl_xor(v, 1, 64); v += __shfl_xor(v, 2, 64);
      if (q == 0) { wsf[256 + o] = u; wsf[320 + o] = b1[o] + v; }
    }
    if (tid < 64) {
      int o = tid >> 2, q = tid & 3;
      float u = 0.f, v = 0.f;
      unsigned short loc[16];
#pragma unroll
      for (int i = 0; i < 16; ++i) {
        int c = q * 16 + i;
        float wv = (o < 6) ? w2[o * 64 + c] : 0.f;
        float wsc = wv * s2[c];
        loc[i] = f2bf(wsc);
        u += wsc;
        v += wv * gb2[c];
      }
      *(short8*)(a2 + o * 64 + q * 16) = *(short8*)loc;
      *(short8*)(a2 + o * 64 + q * 16 + 8) = *(short8*)(loc + 8);
      u += __shfl_xor(u, 1, 64); u += __shfl_xor(u, 2, 64);
      v += __shfl_xor(v, 1, 64); v += __shfl_xor(v, 2, 64);
      if (q == 0) { wsf[384 + o] = u; wsf[400 + o] = ((o < 6) ? b2[o] : 0.f) + v; }
    }
  }

  const f32x4* xb = (const f32x4*)(x + (size_t)b * CH * HW);
  const f32x4* p = xb + (size_t)blockIdx.x * 8192 + tid;
  float s = 0.f, q = 0.f;
#pragma unroll
  for (int it = 0; it < 32; ++it) {
    f32x4 v = p[it * 256];
#pragma unroll
    for (int i = 0; i < 4; ++i) { float f = v[i]; s += f; q += f * f; }
  }
#pragma unroll
  for (int off = 32; off > 0; off >>= 1) {
    s += __shfl_down(s, off, 64);
    q += __shfl_down(q, off, 64);
  }
  if (l == 0) { red[w] = s; red[4 + w] = q; }
  __syncthreads();
  if (tid == 0) {
    atomicAdd(wsf + 16 * b + 0, red[0] + red[1] + red[2] + red[3]);
    atomicAdd(wsf + 16 * b + 1, red[4] + red[5] + red[6] + red[7]);
  }
}

// ---- k2: fat blocks (512 px), WAVE-PRIVATE pipeline, zero intra-loop barriers ----
// wave w owns pixels [w*32, w*32+32) of every subtile: loads, stage, frags, h, y.
__global__ __launch_bounds__(256, 3) void k2(const float* __restrict__ x,
                                             const unsigned short* __restrict__ a1,
                                             const unsigned short* __restrict__ a2,
                                             const float* __restrict__ wsf,
                                             float* __restrict__ wstat,
                                             float* __restrict__ out) {
  __shared__ __align__(16) unsigned char buf[2][128 * 128];
  __shared__ float red[8];
  const int tid = threadIdx.x;
  const int l = tid & 63, w = tid >> 6;
  const int s = 15 - blockIdx.y;                  // reverse sample order
  const int pbase = (127 - blockIdx.x) * 512;     // 512 px per block, reverse
  const float* xb = x + (size_t)s * CH * HW;

  const float m1 = wsf[16 * s + 0] / NPIXF;
  const float rs1 = rsqrtf(wsf[16 * s + 1] / NPIXF - m1 * m1 + 1e-6f);

  float c1r[4][4];
#pragma unroll
  for (int mf = 0; mf < 4; ++mf) {
    const int o0 = mf * 16 + (l >> 4) * 4;
    f32x4 u = *(const f32x4*)(wsf + 256 + o0);
    f32x4 vv = *(const f32x4*)(wsf + 320 + o0);
#pragma unroll
    for (int r = 0; r < 4; ++r) c1r[mf][r] = vv[r] - rs1 * m1 * u[r];
  }

  bf16x8 af[4][2];
#pragma unroll
  for (int mf = 0; mf < 4; ++mf)
#pragma unroll
    for (int ks = 0; ks < 2; ++ks)
      af[mf][ks] = *(const bf16x8*)((const unsigned char*)a1 +
                     (mf * 16 + (l & 15)) * 128 + ks * 64 + (l >> 4) * 16);
  bf16x8 a2f[2];
#pragma unroll
  for (int ks = 0; ks < 2; ++ks)
    a2f[ks] = *(const bf16x8*)((const unsigned char*)a2 +
                 (l & 15) * 128 + ks * 64 + (l >> 4) * 16);

  // wave-private partition: lane = (channel-group l>>3, pixel (l&7)*4) in wave's strip
  const int c0 = (l >> 3) * 8;            // 8 channel-groups per wave
  const int px4 = (l & 7) * 4;            // 8x4 px per channel-group = 32 px strip
  const int prow = w * 32;                // wave's LDS row base
  const float* base = xb + (size_t)c0 * HW + pbase + prow + px4;
  float* ob = out + (size_t)s * 6 * HW;

  // prologue: load + stage subtile 0 (wave-private rows -> no barrier)
  f32x4 v[8];
#pragma unroll
  for (int i = 0; i < 8; ++i) v[i] = *(const f32x4*)(base + (size_t)i * HW);
#pragma unroll
  for (int dp = 0; dp < 4; ++dp) {
    int p = prow + px4 + dp;
    short8 w8;
#pragma unroll
    for (int i = 0; i < 8; ++i) w8[i] = cvt1(v[i][dp]);
    *(short8*)(buf[0] + p * 128 + swz(p, c0 >> 3) * 16) = w8;
  }

  float hs = 0.f, hq = 0.f;
#pragma unroll
  for (int j = 0; j < 4; ++j) {
    const int cur = j & 1;
    const int pt = pbase + j * 128;

    // issue next subtile's loads now; they complete under this subtile's compute
    if (j < 3) {
#pragma unroll
      for (int i = 0; i < 8; ++i)
        v[i] = *(const f32x4*)(base + (size_t)i * HW + (j + 1) * 128);
    }

    // B-fragments from wave-private rows (in-wave LDS ordering, no barrier)
    bf16x8 bfr[2][2];
#pragma unroll
    for (int nf = 0; nf < 2; ++nf) {
      const int pl = prow + nf * 16 + (l & 15);
#pragma unroll
      for (int ks = 0; ks < 2; ++ks) {
        int cc = ks * 4 + (l >> 4);
        bfr[nf][ks] = *(const bf16x8*)(buf[cur] + pl * 128 + swz(pl, cc) * 16);
      }
    }

    // phase A: conv1 + silu + h-stats, h -> buf[cur] (same wave-private rows)
#pragma unroll
    for (int nf = 0; nf < 2; ++nf) {
      const int pl = prow + nf * 16 + (l & 15);
#pragma unroll
      for (int mf = 0; mf < 4; ++mf) {
        f32x4 acc = {0.f, 0.f, 0.f, 0.f};
        acc = __builtin_amdgcn_mfma_f32_16x16x32_bf16(af[mf][0], bfr[nf][0], acc, 0, 0, 0);
        acc = __builtin_amdgcn_mfma_f32_16x16x32_bf16(af[mf][1], bfr[nf][1], acc, 0, 0, 0);
        const int o0 = mf * 16 + (l >> 4) * 4;
        short4v hv;
#pragma unroll
        for (int r = 0; r < 4; ++r) {
          float z = rs1 * acc[r] + c1r[mf][r];
          float hh = z * fastrcp(1.f + __expf(-z));
          hs += hh; hq += hh * hh;
          hv[r] = cvt1(hh);
        }
        *(short4v*)(buf[cur] + pl * 128 + swz(pl, o0 >> 3) * 16 + (o0 & 7) * 2) = hv;
      }
    }

    // phase B: conv2 -> raw y (reads wave-private h rows)
#pragma unroll
    for (int nf = 0; nf < 2; ++nf) {
      const int pl = prow + nf * 16 + (l & 15);
      bf16x8 hfr[2];
#pragma unroll
      for (int ks = 0; ks < 2; ++ks) {
        int cc = ks * 4 + (l >> 4);
        hfr[ks] = *(const bf16x8*)(buf[cur] + pl * 128 + swz(pl, cc) * 16);
      }
      f32x4 acc = {0.f, 0.f, 0.f, 0.f};
      acc = __builtin_amdgcn_mfma_f32_16x16x32_bf16(a2f[0], hfr[0], acc, 0, 0, 0);
      acc = __builtin_amdgcn_mfma_f32_16x16x32_bf16(a2f[1], hfr[1], acc, 0, 0, 0);
      const int ob0 = (l >> 4) * 4;
#pragma unroll
      for (int r = 0; r < 4; ++r) {
        int o = ob0 + r;
        if (o < 6) ob[(size_t)o * HW + pt + pl] = acc[r];
      }
    }

    // stage next subtile into the other buffer (wave-private; no barrier)
    if (j < 3) {
#pragma unroll
      for (int dp = 0; dp < 4; ++dp) {
        int p = prow + px4 + dp;
        short8 w8;
#pragma unroll
        for (int i = 0; i < 8; ++i) w8[i] = cvt1(v[i][dp]);
        *(short8*)(buf[cur ^ 1] + p * 128 + swz(p, c0 >> 3) * 16) = w8;
      }
    }
  }

#pragma unroll
  for (int off = 32; off > 0; off >>= 1) {
    hs += __shfl_down(hs, off, 64);
    hq += __shfl_down(hq, off, 64);
  }
  if (l == 0) { red[w] = hs; red[4 + w] = hq; }
  __syncthreads();
  if (tid == 0) {
    atomicAdd(wstat + 16 * s + 2, red[0] + red[1] + red[2] + red[3]);
    atomicAdd(wstat + 16 * s + 3, red[4] + red[5] + red[6] + red[7]);
  }
}

// ---- k3: out = rs2*out + c2[o]  (in-place, elementwise) ----
__global__ __launch_bounds__(256) void k3(float* __restrict__ out,
                                          const float* __restrict__ wsf) {
  const int s = 15 - blockIdx.y;
  const float m2 = wsf[16 * s + 2] / NPIXF;
  const float rs2 = rsqrtf(wsf[16 * s + 3] / NPIXF - m2 * m2 + 1e-6f);
  float* ob = out + (size_t)s * 6 * HW;
#pragma unroll
  for (int it = 0; it < 4; ++it) {
    int f4 = blockIdx.x * 256 + threadIdx.x + it * 24576;  // < 98304
    int o = f4 >> 14;
    float c2 = wsf[400 + o] - rs2 * m2 * wsf[384 + o];
    f32x4* p = (f32x4*)ob + f4;
    f32x4 v = *p;
#pragma unroll
    for (int i = 0; i < 4; ++i) v[i] = rs2 * v[i] + c2;
    *p = v;
  }
}

extern "C" void kernel_launch(void* const* d_in, const int* in_sizes, int n_in,
                              void* d_out, int out_size, void* d_ws, size_t ws_size,
                              hipStream_t stream) {
  const float* x  = (const float*)d_in[0];
  const float* s1 = (const float*)d_in[1];
  const float* g1 = (const float*)d_in[2];
  const float* w1 = (const float*)d_in[3];
  const float* b1 = (const float*)d_in[4];
  const float* s2 = (const float*)d_in[5];
  const float* g2 = (const float*)d_in[6];
  const float* w2 = (const float*)d_in[7];
  const float* b2 = (const float*)d_in[8];
  float* out = (float*)d_out;
  float* wsf = (float*)d_ws;
  unsigned short* a1 = (unsigned short*)((char*)d_ws + 2048);
  unsigned short* a2 = (unsigned short*)((char*)d_ws + 10240);

  if (ws_size < 16384) return;

  hipMemsetAsync(d_ws, 0, 1024, stream);  // zero per-sample stat lines
  k1<<<dim3(128, 16), 256, 0, stream>>>(x, w1, b1, s1, g1, w2, b2, s2, g2, wsf, a1, a2);
  k2<<<dim3(128, 16), 256, 0, stream>>>(x, a1, a2, wsf, wsf, out);
  k3<<<dim3(96, 16), 256, 0, stream>>>(out, wsf);
}